// Round 15
// baseline (190.876 us; speedup 1.0000x reference)
//
#include <hip/hip_runtime.h>
#include <hip/hip_bf16.h>
#include <math.h>

// B=64, S=512, VOCAB=32000, EMBED=512, HIDDEN=1024, ENC=1024, ATTN=256

typedef float f32x4 __attribute__((ext_vector_type(4)));
typedef short s16x8 __attribute__((ext_vector_type(8)));

__device__ __forceinline__ float sigmoidf_(float x) { return 1.0f / (1.0f + expf(-x)); }

__device__ __forceinline__ ushort f2bf(float f) {
    __hip_bfloat16 h = __float2bfloat16(f);
    return *reinterpret_cast<ushort*>(&h);
}

// ---------------------------------------------------------------------------
// 1. prep: blocks 0..63 embed gather | 64..319 We->bf16 | 320..383 dec_proj
__global__ __launch_bounds__(256) void k_prep(const int* __restrict__ tok,
                                              const float* __restrict__ table,
                                              const float* __restrict__ We,
                                              const float* __restrict__ h0,
                                              const float* __restrict__ Wd,
                                              float* __restrict__ emb,
                                              ushort* __restrict__ Wbf,
                                              float* __restrict__ dp) {
    __shared__ float sh[1024];
    int bx = blockIdx.x;
    int tid = threadIdx.x;
    if (bx < 64) {
        int b = bx;
        int t = tok[b];
        const float4* src = (const float4*)(table + (size_t)t * 512);
        float4* dst = (float4*)(emb + (size_t)b * 512);
        if (tid < 128) dst[tid] = src[tid];
    } else if (bx < 320) {
        int i = (bx - 64) * 256 + tid;
        float4 f = ((const float4*)We)[i];
        ushort4 o;
        o.x = f2bf(f.x); o.y = f2bf(f.y); o.z = f2bf(f.z); o.w = f2bf(f.w);
        ((ushort4*)Wbf)[i] = o;
    } else {
        int b = bx - 320;
        int a = tid;
        for (int i = tid; i < 1024; i += 256) sh[i] = h0[(size_t)b * 1024 + i];
        __syncthreads();
        const float* w = Wd + (size_t)a * 1024;
        float acc = 0.f;
#pragma unroll 4
        for (int k = 0; k < 1024; k += 4) {
            float4 w4 = *(const float4*)(w + k);
            float4 h4 = *(const float4*)(sh + k);
            acc += w4.x * h4.x + w4.y * h4.y + w4.z * h4.z + w4.w * h4.w;
        }
        dp[b * 256 + a] = acc;
    }
}

// ---------------------------------------------------------------------------
// 2. fused scores (MFMA) + mask + chunk softmax + partial context.
//    T3/T4 counted-vmcnt pipeline at r10 geometry: grid 1024 = (b, 16
//    s-chunks of 32), 3 blocks/CU. BK=32, depth-2 double-buffer. ALL staging
//    via global_load_lds (1 A + 4 B per thread per chunk); A stored f32 in
//    LDS (converted at consume), B bf16. s_waitcnt vmcnt(5) + raw s_barrier:
//    the next chunk's 5 loads stay in flight across barriers (never drain
//    to 0 until the peeled last chunk). No sched_barrier pinning.
__global__ __launch_bounds__(256, 3) void k_scores_ctx(const float* __restrict__ enc,
                                                       const ushort* __restrict__ Wbf,
                                                       const float* __restrict__ dp,
                                                       const float* __restrict__ v,
                                                       const unsigned* __restrict__ mask,
                                                       float* __restrict__ scores,
                                                       float* __restrict__ stats,
                                                       float* __restrict__ ctxp) {
    int b  = blockIdx.x >> 4;
    int sc = blockIdx.x & 15;
    int s0 = sc << 5;
    int tid = threadIdx.x;
    int wave = tid >> 6, lane = tid & 63;
    int lan = lane & 15, lk = lane >> 4;

    __shared__ float4 Af[2][256];    // 2 x 4 KB : slot row*8 + (kslot ^ (row&7))
    __shared__ s16x8  Bf[2][1024];   // 2 x 16 KB: slot a*4 + (koct ^ ((a>>1)&3))
    __shared__ float sdp[256], sv[256];
    __shared__ float wpart[4][32];
    __shared__ float ps[32];
    __shared__ int flag;

    sdp[tid] = dp[b * 256 + tid];
    sv[tid]  = v[tid];
    int bad = 0;
    for (int i = tid; i < 512; i += 256)
        if (mask[i] > 1u) bad = 1;
    if (tid == 0) flag = 0;
    __syncthreads();
    if (bad) atomicOr(&flag, 1);

    const float* encB = enc + ((size_t)(b * 512 + s0)) * 1024;

    // stage chunk t (k0 = t*32) into buffer bi: 1 A + 4 B gld_lds per thread.
    // A: dest slot d = tid (linear); row=d>>3, kslot_src=(d&7)^(row&7).
    // B: dest slot d = it*256+wave*64+lane; a=d>>2, koct_src=(d&3)^((a>>1)&3).
    auto stage = [&](int bi, int k0) {
        {
            int d = tid;
            int row = d >> 3, j = d & 7;
            const float* src = encB + (size_t)row * 1024 + k0 + ((j ^ (row & 7)) << 2);
            __builtin_amdgcn_global_load_lds(
                (const __attribute__((address_space(1))) void*)src,
                (__attribute__((address_space(3))) void*)&Af[bi][wave * 64],
                16, 0, 0);
        }
#pragma unroll
        for (int it = 0; it < 4; ++it) {
            int dbase = it * 256 + wave * 64;
            int d = dbase + lane;
            int a = d >> 2, j = d & 3;
            const ushort* src = Wbf + (size_t)a * 1024 + k0 + ((j ^ ((a >> 1) & 3)) << 3);
            __builtin_amdgcn_global_load_lds(
                (const __attribute__((address_space(1))) void*)src,
                (__attribute__((address_space(3))) void*)&Bf[bi][dbase],
                16, 0, 0);
        }
    };

    f32x4 acc[2][4];
#pragma unroll
    for (int rf = 0; rf < 2; ++rf)
#pragma unroll
        for (int ni = 0; ni < 4; ++ni) acc[rf][ni] = (f32x4){0.f, 0.f, 0.f, 0.f};

    // counted-vmcnt regime: drain all prior vmem first
    asm volatile("s_waitcnt vmcnt(0)" ::: "memory");
    stage(0, 0);
    stage(1, 32);                      // 10 outstanding per wave

    for (int t = 0; t < 32; ++t) {
        if (t < 31) asm volatile("s_waitcnt vmcnt(5)" ::: "memory");  // chunk t landed
        else        asm volatile("s_waitcnt vmcnt(0)" ::: "memory");  // last chunk
        __builtin_amdgcn_s_barrier();

        int cur = t & 1;
        // A fragments: f32 from LDS, convert in-reg. row k-range = 32.
        s16x8 af[2];
#pragma unroll
        for (int rf = 0; rf < 2; ++rf) {
            int row = rf * 16 + lan;
            int r7 = row & 7;
            float4 x = Af[cur][row * 8 + ((lk * 2) ^ r7)];
            float4 y = Af[cur][row * 8 + ((lk * 2 + 1) ^ r7)];
            s16x8 p;
            p[0] = (short)f2bf(x.x); p[1] = (short)f2bf(x.y);
            p[2] = (short)f2bf(x.z); p[3] = (short)f2bf(x.w);
            p[4] = (short)f2bf(y.x); p[5] = (short)f2bf(y.y);
            p[6] = (short)f2bf(y.z); p[7] = (short)f2bf(y.w);
            af[rf] = p;
        }
#pragma unroll
        for (int ni = 0; ni < 4; ++ni) {
            int a = wave * 64 + ni * 16 + lan;
            s16x8 bf = Bf[cur][a * 4 + (lk ^ ((a >> 1) & 3))];
#pragma unroll
            for (int rf = 0; rf < 2; ++rf)
                acc[rf][ni] = __builtin_amdgcn_mfma_f32_16x16x32_bf16(af[rf], bf, acc[rf][ni], 0, 0, 0);
        }
        // my ds_reads retired (data in regs) before anyone overwrites buf cur
        asm volatile("s_waitcnt lgkmcnt(0)" ::: "memory");
        __builtin_amdgcn_s_barrier();
        if (t + 2 < 32) stage(cur, (t + 2) * 32);
    }

    // epilogue: wave-partial col-sums of tanh(acc+dp)*v over its 64 cols.
    // D layout: row (in chunk) = rf*16 + lk*4 + r, col = wave*64 + ni*16 + lan.
    float rs[2][4];
#pragma unroll
    for (int rf = 0; rf < 2; ++rf)
#pragma unroll
        for (int r = 0; r < 4; ++r) rs[rf][r] = 0.f;
#pragma unroll
    for (int rf = 0; rf < 2; ++rf) {
#pragma unroll
        for (int ni = 0; ni < 4; ++ni) {
            int a = wave * 64 + ni * 16 + lan;
            float dpv = sdp[a], vv = sv[a];
#pragma unroll
            for (int r = 0; r < 4; ++r) {
                float x = acc[rf][ni][r] + dpv;
                float th = 1.f - 2.f / (1.f + __expf(2.f * x));
                rs[rf][r] += th * vv;
            }
        }
    }
#pragma unroll
    for (int off = 1; off < 16; off <<= 1) {
#pragma unroll
        for (int rf = 0; rf < 2; ++rf)
#pragma unroll
            for (int r = 0; r < 4; ++r) rs[rf][r] += __shfl_xor(rs[rf][r], off);
    }
    if (lan == 0) {
#pragma unroll
        for (int rf = 0; rf < 2; ++rf)
#pragma unroll
            for (int r = 0; r < 4; ++r)
                wpart[wave][rf * 16 + lk * 4 + r] = rs[rf][r];
    }
    __syncthreads();

    bool u8 = (flag != 0);
    if (tid < 32) {
        int s = s0 + tid;
        float val = wpart[0][tid] + wpart[1][tid] + wpart[2][tid] + wpart[3][tid];
        bool m = u8 ? (((const unsigned char*)mask)[(size_t)b * 512 + s] != 0)
                    : (mask[(size_t)b * 512 + s] != 0u);
        val = m ? val : -1e9f;
        scores[(size_t)b * 512 + s] = val;
        float mx = val;
#pragma unroll
        for (int off = 1; off < 32; off <<= 1) mx = fmaxf(mx, __shfl_xor(mx, off));
        float e = __expf(val - mx);
        float sum = e;
#pragma unroll
        for (int off = 1; off < 32; off <<= 1) sum += __shfl_xor(sum, off);
        ps[tid] = e;
        if (tid == 0) {
            stats[((size_t)b * 16 + sc) * 2]     = mx;
            stats[((size_t)b * 16 + sc) * 2 + 1] = sum;
        }
    }
    __syncthreads();

    // PV: partial context over this chunk's 32 rows (enc tile L2/L3-warm)
    f32x4 cacc = (f32x4){0.f, 0.f, 0.f, 0.f};
    const float* eb = encB + tid * 4;
#pragma unroll 8
    for (int s = 0; s < 32; ++s) {
        f32x4 ev = *(const f32x4*)(eb + (size_t)s * 1024);
        float pv = ps[s];
        cacc += pv * ev;
    }
    *(f32x4*)(ctxp + ((size_t)(b * 16 + sc)) * 1024 + tid * 4) = cacc;
}

// ---------------------------------------------------------------------------
// 3. combine 16 chunk partials -> ctx, out_w. grid 64 (one block per b).
__global__ __launch_bounds__(256) void k_ctx_fin(const float* __restrict__ stats,
                                                 const float* __restrict__ scores,
                                                 const float* __restrict__ ctxp,
                                                 float* __restrict__ out_w,
                                                 float* __restrict__ ctx) {
    int b = blockIdx.x;
    int tid = threadIdx.x;
    __shared__ float sm[16], ssum[16];
    if (tid < 16) {
        sm[tid]   = stats[((size_t)b * 16 + tid) * 2];
        ssum[tid] = stats[((size_t)b * 16 + tid) * 2 + 1];
    }
    __syncthreads();
    float M = sm[0];
#pragma unroll
    for (int i = 1; i < 16; ++i) M = fmaxf(M, sm[i]);
    float total = 0.f;
#pragma unroll
    for (int i = 0; i < 16; ++i) total += ssum[i] * __expf(sm[i] - M);
    float inv = 1.f / total;

    out_w[(size_t)b * 512 + tid]       = __expf(scores[(size_t)b * 512 + tid] - M) * inv;
    out_w[(size_t)b * 512 + tid + 256] = __expf(scores[(size_t)b * 512 + tid + 256] - M) * inv;

    f32x4 acc = (f32x4){0.f, 0.f, 0.f, 0.f};
#pragma unroll
    for (int sc = 0; sc < 16; ++sc) {
        float w = __expf(sm[sc] - M) * inv;
        f32x4 p = *(const f32x4*)(ctxp + ((size_t)(b * 16 + sc)) * 1024 + tid * 4);
        acc += w * p;
    }
    *(f32x4*)(ctx + (size_t)b * 1024 + tid * 4) = acc;
}

// ---------------------------------------------------------------------------
// 4. gates partial GEMM. grid (64 j-tiles of 64, 8 K-chunks of 320).
__global__ __launch_bounds__(256) void k_gates_part(const float* __restrict__ emb,
                                                    const float* __restrict__ ctx,
                                                    const float* __restrict__ h,
                                                    const float* __restrict__ Wih,
                                                    const float* __restrict__ Whh,
                                                    float* __restrict__ p0,
                                                    float* __restrict__ p7) {
    int j0 = blockIdx.x * 64;
    int kc = blockIdx.y;
    __shared__ float Xs[64][33];
    __shared__ float Ws[64][33];
    int tid = threadIdx.x;
    int tx = tid & 15, ty = tid >> 4;
    float acc[4][4];
#pragma unroll
    for (int i = 0; i < 4; ++i)
#pragma unroll
        for (int j = 0; j < 4; ++j) acc[i][j] = 0.f;

    for (int k0 = kc * 320; k0 < kc * 320 + 320; k0 += 32) {
        const float* xsrc; int xstride, xoff;
        if (k0 < 512)       { xsrc = emb; xstride = 512;  xoff = k0; }
        else if (k0 < 1536) { xsrc = ctx; xstride = 1024; xoff = k0 - 512; }
        else                { xsrc = h;   xstride = 1024; xoff = k0 - 1536; }
        const float* wsrc; int wstride, woff;
        if (k0 < 1536) { wsrc = Wih; wstride = 1536; woff = k0; }
        else           { wsrc = Whh; wstride = 1024; woff = k0 - 1536; }
        __syncthreads();
#pragma unroll
        for (int i = 0; i < 8; ++i) {
            int idx = tid + i * 256;
            int kk = idx & 31, bb = idx >> 5;
            Xs[bb][kk] = xsrc[(size_t)bb * xstride + xoff + kk];
        }
#pragma unroll
        for (int i = 0; i < 8; ++i) {
            int idx = tid + i * 256;
            int kk = idx & 31, jj = idx >> 5;
            Ws[jj][kk] = wsrc[(size_t)(j0 + jj) * wstride + woff + kk];
        }
        __syncthreads();
#pragma unroll
        for (int kk = 0; kk < 32; ++kk) {
            float x0 = Xs[ty * 4 + 0][kk];
            float x1 = Xs[ty * 4 + 1][kk];
            float x2 = Xs[ty * 4 + 2][kk];
            float x3 = Xs[ty * 4 + 3][kk];
            float w0 = Ws[tx * 4 + 0][kk];
            float w1 = Ws[tx * 4 + 1][kk];
            float w2 = Ws[tx * 4 + 2][kk];
            float w3 = Ws[tx * 4 + 3][kk];
            acc[0][0] += x0 * w0; acc[0][1] += x0 * w1; acc[0][2] += x0 * w2; acc[0][3] += x0 * w3;
            acc[1][0] += x1 * w0; acc[1][1] += x1 * w1; acc[1][2] += x1 * w2; acc[1][3] += x1 * w3;
            acc[2][0] += x2 * w0; acc[2][1] += x2 * w1; acc[2][2] += x2 * w2; acc[2][3] += x2 * w3;
            acc[3][0] += x3 * w0; acc[3][1] += x3 * w1; acc[3][2] += x3 * w2; acc[3][3] += x3 * w3;
        }
    }
    float* dst = (kc < 7) ? (p0 + (size_t)kc * 262144) : p7;
#pragma unroll
    for (int ri = 0; ri < 4; ++ri) {
        int bb = ty * 4 + ri;
#pragma unroll
        for (int cj = 0; cj < 4; ++cj)
            dst[(size_t)bb * 4096 + j0 + tx * 4 + cj] = acc[ri][cj];
    }
}

// ---------------------------------------------------------------------------
// 5. LSTM elementwise + 8-way partial reduce
__global__ __launch_bounds__(256) void k_lstm(const float* __restrict__ p0,
                                              const float* __restrict__ p7,
                                              const float* __restrict__ bih,
                                              const float* __restrict__ bhh,
                                              const float* __restrict__ c0,
                                              float* __restrict__ out_h,
                                              float* __restrict__ out_c) {
    int idx = blockIdx.x * 256 + threadIdx.x;
    int b = idx >> 10, hh = idx & 1023;
    float g[4];
#pragma unroll
    for (int gt = 0; gt < 4; ++gt) {
        size_t off = (size_t)b * 4096 + gt * 1024 + hh;
        float s = p7[off] + bih[gt * 1024 + hh] + bhh[gt * 1024 + hh];
#pragma unroll
        for (int kc = 0; kc < 7; ++kc) s += p0[(size_t)kc * 262144 + off];
        g[gt] = s;
    }
    float c_old = c0[idx];
    float nc = sigmoidf_(g[1]) * c_old + sigmoidf_(g[0]) * tanhf(g[2]);
    float nh = sigmoidf_(g[3]) * tanhf(nc);
    out_h[idx] = nh;
    out_c[idx] = nc;
}

// ---------------------------------------------------------------------------
// 6a. readout partials: grid (32 j-tiles of 16, 16 K-chunks of 160).
__global__ __launch_bounds__(256) void k_readout_part(const float* __restrict__ nh,
                                                      const float* __restrict__ ctx,
                                                      const float* __restrict__ emb,
                                                      const float* __restrict__ Wo,
                                                      float* __restrict__ Tp) {
    int j0 = blockIdx.x * 16;
    int kc = blockIdx.y;
    __shared__ float Xs[64][33];
    __shared__ float Ws[16][33];
    int tid = threadIdx.x;
    int b = tid & 63, jg = tid >> 6;
    float acc[4] = {0.f, 0.f, 0.f, 0.f};

    for (int k0 = kc * 160; k0 < kc * 160 + 160; k0 += 32) {
        const float* xsrc; int xstride, xoff;
        if (k0 < 1024)      { xsrc = nh;  xstride = 1024; xoff = k0; }
        else if (k0 < 2048) { xsrc = ctx; xstride = 1024; xoff = k0 - 1024; }
        else                { xsrc = emb; xstride = 512;  xoff = k0 - 2048; }
        __syncthreads();
#pragma unroll
        for (int i = 0; i < 8; ++i) {
            int idx = tid + i * 256;
            int kk = idx & 31, bb = idx >> 5;
            Xs[bb][kk] = xsrc[(size_t)bb * xstride + xoff + kk];
        }
#pragma unroll
        for (int i = 0; i < 2; ++i) {
            int idx = tid + i * 256;
            int kk = idx & 31, jj = idx >> 5;
            Ws[jj][kk] = Wo[(size_t)(j0 + jj) * 2560 + k0 + kk];
        }
        __syncthreads();
#pragma unroll
        for (int kk = 0; kk < 32; ++kk) {
            float x = Xs[b][kk];
            acc[0] += x * Ws[jg * 4 + 0][kk];
            acc[1] += x * Ws[jg * 4 + 1][kk];
            acc[2] += x * Ws[jg * 4 + 2][kk];
            acc[3] += x * Ws[jg * 4 + 3][kk];
        }
    }
#pragma unroll
    for (int c = 0; c < 4; ++c)
        Tp[((size_t)kc * 64 + b) * 512 + j0 + jg * 4 + c] = acc[c];
}

// 6b. readout finish: T = tanh(sum 16 partials + bias)
__global__ __launch_bounds__(256) void k_readout_fin(const float* __restrict__ Tp,
                                                     const float* __restrict__ bo,
                                                     float* __restrict__ T) {
    int i = blockIdx.x * 256 + threadIdx.x;
    int j = i & 511;
    float s = 0.f;
#pragma unroll
    for (int kc = 0; kc < 16; ++kc) s += Tp[(size_t)kc * 32768 + i];
    T[i] = tanhf(s + bo[j]);
}

// ---------------------------------------------------------------------------
// 7. logits via MFMA, barrier-free main loop. grid 500 x 256 thr (4 waves).
__global__ __launch_bounds__(256, 2) void k_logits(const float* __restrict__ T,
                                                   const float* __restrict__ table,
                                                   float* __restrict__ out) {
    int tid = threadIdx.x;
    int wave = tid >> 6, lane = tid & 63;
    int lan = lane & 15, lk = lane >> 4;

    __shared__ s16x8 Tl[4096];   // 64 KB: slot b*64 + (koct ^ (b&7)), koct 0..63

#pragma unroll
    for (int it = 0; it < 16; ++it) {
        int idx = tid + it * 256;
        int b = idx >> 6, koct = idx & 63;
        const float* src = T + (size_t)b * 512 + koct * 8;
        float4 f0 = *(const float4*)src;
        float4 f1 = *(const float4*)(src + 4);
        s16x8 pk;
        pk[0] = (short)f2bf(f0.x); pk[1] = (short)f2bf(f0.y);
        pk[2] = (short)f2bf(f0.z); pk[3] = (short)f2bf(f0.w);
        pk[4] = (short)f2bf(f1.x); pk[5] = (short)f2bf(f1.y);
        pk[6] = (short)f2bf(f1.z); pk[7] = (short)f2bf(f1.w);
        Tl[b * 64 + (koct ^ (b & 7))] = pk;
    }
    __syncthreads();

    int v0 = blockIdx.x * 64 + wave * 16;
    const float* tabRow = table + (size_t)(v0 + lan) * 512 + lk * 8;

    f32x4 acc[4];
#pragma unroll
    for (int ni = 0; ni < 4; ++ni) acc[ni] = (f32x4){0.f, 0.f, 0.f, 0.f};

    float4 pa0 = *(const float4*)(tabRow);
    float4 pa1 = *(const float4*)(tabRow + 4);
    float4 pb0 = *(const float4*)(tabRow + 32);
    float4 pb1 = *(const float4*)(tabRow + 36);

    for (int t = 0; t < 16; ++t) {
        float4 pc0 = {0.f, 0.f, 0.f, 0.f}, pc1 = {0.f, 0.f, 0.f, 0.f};
        if (t < 14) {
            pc0 = *(const float4*)(tabRow + (t + 2) * 32);
            pc1 = *(const float4*)(tabRow + (t + 2) * 32 + 4);
        }
        s16x8 af;
        af[0] = (short)f2bf(pa0.x); af[1] = (short)f2bf(pa0.y);
        af[2] = (short)f2bf(pa0.z); af[3] = (short)f2bf(pa0.w);
        af[4] = (short)f2bf(pa1.x); af[5] = (short)f2bf(pa1.y);
        af[6] = (short)f2bf(pa1.z); af[7] = (short)f2bf(pa1.w);
        int akoct = t * 4 + lk;
#pragma unroll
        for (int ni = 0; ni < 4; ++ni) {
            int bg = ni * 16 + lan;
            s16x8 bf = Tl[bg * 64 + (akoct ^ (bg & 7))];
            acc[ni] = __builtin_amdgcn_mfma_f32_16x16x32_bf16(af, bf, acc[ni], 0, 0, 0);
        }
        pa0 = pb0; pa1 = pb1; pb0 = pc0; pb1 = pc1;
    }

#pragma unroll
    for (int ni = 0; ni < 4; ++ni) {
        int bg = ni * 16 + lan;
        float4 o;
        o.x = acc[ni][0]; o.y = acc[ni][1]; o.z = acc[ni][2]; o.w = acc[ni][3];
        *(float4*)(out + (size_t)bg * 32000 + v0 + lk * 4) = o;
    }
}

// ---------------------------------------------------------------------------
extern "C" void kernel_launch(void* const* d_in, const int* in_sizes, int n_in,
                              void* d_out, int out_size, void* d_ws, size_t ws_size,
                              hipStream_t stream) {
    const int*      tok   = (const int*)d_in[0];
    const float*    h0    = (const float*)d_in[1];
    const float*    c0    = (const float*)d_in[2];
    const float*    enc   = (const float*)d_in[3];
    const unsigned* mask  = (const unsigned*)d_in[4];
    const float*    table = (const float*)d_in[5];
    const float*    We    = (const float*)d_in[6];
    const float*    Wd    = (const float*)d_in[7];
    const float*    va    = (const float*)d_in[8];
    const float*    Wih   = (const float*)d_in[9];
    const float*    Whh   = (const float*)d_in[10];
    const float*    bih   = (const float*)d_in[11];
    const float*    bhh   = (const float*)d_in[12];
    const float*    Wo    = (const float*)d_in[13];
    const float*    bo    = (const float*)d_in[14];

    float* out    = (float*)d_out;
    float* logits = out;                      // 64*32000 = 2048000
    float* out_h  = out + 2048000;            // 65536
    float* out_c  = out + 2048000 + 65536;    // 65536
    float* out_w  = out + 2048000 + 131072;   // 32768

    float* ws     = (float*)d_ws;
    float* emb    = ws;             // 32768
    float* dp     = ws + 32768;     // 16384
    float* scores = ws + 49152;     // 32768
    float* ctx    = ws + 81920;     // 65536
    float* big    = ws + 147456;    // 524288 floats (gates p7 / readout Tp)
    float* T      = ws + 671744;    // 32768
    ushort* Wbf   = (ushort*)(ws + 704512);   // 262144 bf16 (131072 float-slots)
    float* stats  = ws + 835584;    // 2048

    float* ctxp     = logits;       // 64*16*1024 = 1M floats, consumed by k_ctx_fin
    float* gates_p0 = logits;       // kc 0..6 partials (after ctxp consumed)
    float* gates_p7 = big;          // kc 7 partial
    float* Tp       = big;          // readout partials (after k_lstm consumed gates)

    k_prep        <<<384, 256, 0, stream>>>(tok, table, We, h0, Wd, emb, Wbf, dp);
    k_scores_ctx  <<<1024, 256, 0, stream>>>(enc, Wbf, dp, va, mask, scores, stats, ctxp);
    k_ctx_fin     <<<64, 256, 0, stream>>>(stats, scores, ctxp, out_w, ctx);
    k_gates_part  <<<dim3(64, 8), 256, 0, stream>>>(emb, ctx, h0, Wih, Whh, gates_p0, gates_p7);
    k_lstm        <<<256, 256, 0, stream>>>(gates_p0, gates_p7, bih, bhh, c0, out_h, out_c);
    k_readout_part<<<dim3(32, 16), 256, 0, stream>>>(out_h, ctx, emb, Wo, Tp);
    k_readout_fin <<<128, 256, 0, stream>>>(Tp, bo, T);
    k_logits      <<<500, 256, 0, stream>>>(T, table, logits);
}

// Round 16
// 149.778 us; speedup vs baseline: 1.2744x; 1.2744x over previous
//
#include <hip/hip_runtime.h>
#include <hip/hip_bf16.h>
#include <math.h>

// B=64, S=512, VOCAB=32000, EMBED=512, HIDDEN=1024, ENC=1024, ATTN=256

typedef float f32x4 __attribute__((ext_vector_type(4)));
typedef short s16x8 __attribute__((ext_vector_type(8)));

__device__ __forceinline__ float sigmoidf_(float x) { return 1.0f / (1.0f + expf(-x)); }

__device__ __forceinline__ ushort f2bf(float f) {
    __hip_bfloat16 h = __float2bfloat16(f);
    return *reinterpret_cast<ushort*>(&h);
}

// ---------------------------------------------------------------------------
// 1. prep: blocks 0..63 embed gather | 64..319 We->bf16 | 320..383 dec_proj
__global__ __launch_bounds__(256) void k_prep(const int* __restrict__ tok,
                                              const float* __restrict__ table,
                                              const float* __restrict__ We,
                                              const float* __restrict__ h0,
                                              const float* __restrict__ Wd,
                                              float* __restrict__ emb,
                                              ushort* __restrict__ Wbf,
                                              float* __restrict__ dp) {
    __shared__ float sh[1024];
    int bx = blockIdx.x;
    int tid = threadIdx.x;
    if (bx < 64) {
        int b = bx;
        int t = tok[b];
        const float4* src = (const float4*)(table + (size_t)t * 512);
        float4* dst = (float4*)(emb + (size_t)b * 512);
        if (tid < 128) dst[tid] = src[tid];
    } else if (bx < 320) {
        int i = (bx - 64) * 256 + tid;
        float4 f = ((const float4*)We)[i];
        ushort4 o;
        o.x = f2bf(f.x); o.y = f2bf(f.y); o.z = f2bf(f.z); o.w = f2bf(f.w);
        ((ushort4*)Wbf)[i] = o;
    } else {
        int b = bx - 320;
        int a = tid;
        for (int i = tid; i < 1024; i += 256) sh[i] = h0[(size_t)b * 1024 + i];
        __syncthreads();
        const float* w = Wd + (size_t)a * 1024;
        float acc = 0.f;
#pragma unroll 4
        for (int k = 0; k < 1024; k += 4) {
            float4 w4 = *(const float4*)(w + k);
            float4 h4 = *(const float4*)(sh + k);
            acc += w4.x * h4.x + w4.y * h4.y + w4.z * h4.z + w4.w * h4.w;
        }
        dp[b * 256 + a] = acc;
    }
}

// ---------------------------------------------------------------------------
// 2. fused scores (MFMA) + mask + chunk softmax + partial context.
//    [r14 best-measured: 82.7us] r10 geometry: grid 1024 = (b, 16 s-chunks
//    of 32), 4 blocks/CU, wave tile 32x64 (2rf x 4ni), XOR-swizzled LDS,
//    T14 register double-buffer staging.
__global__ __launch_bounds__(256, 4) void k_scores_ctx(const float* __restrict__ enc,
                                                       const ushort* __restrict__ Wbf,
                                                       const float* __restrict__ dp,
                                                       const float* __restrict__ v,
                                                       const unsigned* __restrict__ mask,
                                                       float* __restrict__ scores,
                                                       float* __restrict__ stats,
                                                       float* __restrict__ ctxp) {
    int b  = blockIdx.x >> 4;
    int sc = blockIdx.x & 15;
    int s0 = sc << 5;
    int tid = threadIdx.x;
    int wave = tid >> 6, lane = tid & 63;
    int lan = lane & 15, lk = lane >> 4;

    __shared__ s16x8 Al[256];    // 4 KB : 32 rows x 8 koct, slot row*8+(koct^(row&7))
    __shared__ s16x8 Bl[2048];   // 32 KB: 256 a  x 8 koct, slot a*8+(koct^(a&7))
    __shared__ float sdp[256], sv[256];
    __shared__ float wpart[4][32];
    __shared__ float ps[32];
    __shared__ int flag;

    sdp[tid] = dp[b * 256 + tid];
    sv[tid]  = v[tid];
    int bad = 0;
    for (int i = tid; i < 512; i += 256)
        if (mask[i] > 1u) bad = 1;
    if (tid == 0) flag = 0;
    __syncthreads();
    if (bad) atomicOr(&flag, 1);

    const float* encB = enc + ((size_t)(b * 512 + s0)) * 1024;

    int arow = tid >> 3, akoct8 = tid & 7;            // A: 1 slot/thread
    const float* aSrcBase = encB + (size_t)arow * 1024 + akoct8 * 8;

    f32x4 acc[2][4];
#pragma unroll
    for (int rf = 0; rf < 2; ++rf)
#pragma unroll
        for (int ni = 0; ni < 4; ++ni) acc[rf][ni] = (f32x4){0.f, 0.f, 0.f, 0.f};

    float4 rA0, rA1;
    s16x8 rB[8];

    rA0 = *(const float4*)(aSrcBase);
    rA1 = *(const float4*)(aSrcBase + 4);
#pragma unroll
    for (int it = 0; it < 8; ++it) {
        int idx = tid + it * 256;
        int a = idx >> 3, koct = idx & 7;
        rB[it] = *(const s16x8*)(Wbf + (size_t)a * 1024 + 0 + koct * 8);
    }

    for (int t = 0; t < 16; ++t) {
        __syncthreads();
        {
            s16x8 pk;
            pk[0] = (short)f2bf(rA0.x); pk[1] = (short)f2bf(rA0.y);
            pk[2] = (short)f2bf(rA0.z); pk[3] = (short)f2bf(rA0.w);
            pk[4] = (short)f2bf(rA1.x); pk[5] = (short)f2bf(rA1.y);
            pk[6] = (short)f2bf(rA1.z); pk[7] = (short)f2bf(rA1.w);
            Al[arow * 8 + (akoct8 ^ (arow & 7))] = pk;
        }
#pragma unroll
        for (int it = 0; it < 8; ++it) {
            int idx = tid + it * 256;
            int a = idx >> 3, koct = idx & 7;
            Bl[a * 8 + (koct ^ (a & 7))] = rB[it];
        }
        if (t < 15) {
            int k1 = (t + 1) * 64;
            rA0 = *(const float4*)(aSrcBase + k1);
            rA1 = *(const float4*)(aSrcBase + k1 + 4);
#pragma unroll
            for (int it = 0; it < 8; ++it) {
                int idx = tid + it * 256;
                int a = idx >> 3, koct = idx & 7;
                rB[it] = *(const s16x8*)(Wbf + (size_t)a * 1024 + k1 + koct * 8);
            }
        }
        __syncthreads();
#pragma unroll
        for (int ks = 0; ks < 2; ++ks) {
            int akoct = ks * 4 + lk;
            s16x8 af[2];
#pragma unroll
            for (int rf = 0; rf < 2; ++rf) {
                int row = rf * 16 + lan;
                af[rf] = Al[row * 8 + (akoct ^ (row & 7))];
            }
#pragma unroll
            for (int ni = 0; ni < 4; ++ni) {
                int a = wave * 64 + ni * 16 + lan;
                s16x8 bf = Bl[a * 8 + (akoct ^ (a & 7))];
#pragma unroll
                for (int rf = 0; rf < 2; ++rf)
                    acc[rf][ni] = __builtin_amdgcn_mfma_f32_16x16x32_bf16(af[rf], bf, acc[rf][ni], 0, 0, 0);
            }
        }
    }

    float rs[2][4];
#pragma unroll
    for (int rf = 0; rf < 2; ++rf)
#pragma unroll
        for (int r = 0; r < 4; ++r) rs[rf][r] = 0.f;
#pragma unroll
    for (int rf = 0; rf < 2; ++rf) {
#pragma unroll
        for (int ni = 0; ni < 4; ++ni) {
            int a = wave * 64 + ni * 16 + lan;
            float dpv = sdp[a], vv = sv[a];
#pragma unroll
            for (int r = 0; r < 4; ++r) {
                float x = acc[rf][ni][r] + dpv;
                float th = 1.f - 2.f / (1.f + __expf(2.f * x));
                rs[rf][r] += th * vv;
            }
        }
    }
#pragma unroll
    for (int off = 1; off < 16; off <<= 1) {
#pragma unroll
        for (int rf = 0; rf < 2; ++rf)
#pragma unroll
            for (int r = 0; r < 4; ++r) rs[rf][r] += __shfl_xor(rs[rf][r], off);
    }
    if (lan == 0) {
#pragma unroll
        for (int rf = 0; rf < 2; ++rf)
#pragma unroll
            for (int r = 0; r < 4; ++r)
                wpart[wave][rf * 16 + lk * 4 + r] = rs[rf][r];
    }
    __syncthreads();

    bool u8 = (flag != 0);
    if (tid < 32) {
        int s = s0 + tid;
        float val = wpart[0][tid] + wpart[1][tid] + wpart[2][tid] + wpart[3][tid];
        bool m = u8 ? (((const unsigned char*)mask)[(size_t)b * 512 + s] != 0)
                    : (mask[(size_t)b * 512 + s] != 0u);
        val = m ? val : -1e9f;
        scores[(size_t)b * 512 + s] = val;
        float mx = val;
#pragma unroll
        for (int off = 1; off < 32; off <<= 1) mx = fmaxf(mx, __shfl_xor(mx, off));
        float e = __expf(val - mx);
        float sum = e;
#pragma unroll
        for (int off = 1; off < 32; off <<= 1) sum += __shfl_xor(sum, off);
        ps[tid] = e;
        if (tid == 0) {
            stats[((size_t)b * 16 + sc) * 2]     = mx;
            stats[((size_t)b * 16 + sc) * 2 + 1] = sum;
        }
    }
    __syncthreads();

    f32x4 cacc = (f32x4){0.f, 0.f, 0.f, 0.f};
    const float* eb = encB + tid * 4;
#pragma unroll 8
    for (int s = 0; s < 32; ++s) {
        f32x4 ev = *(const f32x4*)(eb + (size_t)s * 1024);
        float pv = ps[s];
        cacc += pv * ev;
    }
    *(f32x4*)(ctxp + ((size_t)(b * 16 + sc)) * 1024 + tid * 4) = cacc;
}

// ---------------------------------------------------------------------------
// 3. combine 16 chunk partials -> ctx, out_w. grid 64 (one block per b).
__global__ __launch_bounds__(256) void k_ctx_fin(const float* __restrict__ stats,
                                                 const float* __restrict__ scores,
                                                 const float* __restrict__ ctxp,
                                                 float* __restrict__ out_w,
                                                 float* __restrict__ ctx) {
    int b = blockIdx.x;
    int tid = threadIdx.x;
    __shared__ float sm[16], ssum[16];
    if (tid < 16) {
        sm[tid]   = stats[((size_t)b * 16 + tid) * 2];
        ssum[tid] = stats[((size_t)b * 16 + tid) * 2 + 1];
    }
    __syncthreads();
    float M = sm[0];
#pragma unroll
    for (int i = 1; i < 16; ++i) M = fmaxf(M, sm[i]);
    float total = 0.f;
#pragma unroll
    for (int i = 0; i < 16; ++i) total += ssum[i] * __expf(sm[i] - M);
    float inv = 1.f / total;

    out_w[(size_t)b * 512 + tid]       = __expf(scores[(size_t)b * 512 + tid] - M) * inv;
    out_w[(size_t)b * 512 + tid + 256] = __expf(scores[(size_t)b * 512 + tid + 256] - M) * inv;

    f32x4 acc = (f32x4){0.f, 0.f, 0.f, 0.f};
#pragma unroll
    for (int sc = 0; sc < 16; ++sc) {
        float w = __expf(sm[sc] - M) * inv;
        f32x4 p = *(const f32x4*)(ctxp + ((size_t)(b * 16 + sc)) * 1024 + tid * 4);
        acc += w * p;
    }
    *(f32x4*)(ctx + (size_t)b * 1024 + tid * 4) = acc;
}

// ---------------------------------------------------------------------------
// 4. gates via MFMA, barrier-free W stream (logits-style). grid (64 j-tiles
//    of 64, 8 K-chunks of 320), 256 thr. X-slice [64 b x 320 k] staged ONCE
//    as swizzled bf16 (40 KB); W rows streamed per-wave coalesced f32 with
//    depth-2 register prefetch. A=W(16 j), B=X(16 b): D col=lan->b,
//    row=lk*4+r->j. Partials p0 (kc<7) / p7 as before; k_lstm unchanged.
__global__ __launch_bounds__(256, 2) void k_gates_mfma(const float* __restrict__ emb,
                                                       const float* __restrict__ ctx,
                                                       const float* __restrict__ h,
                                                       const float* __restrict__ Wih,
                                                       const float* __restrict__ Whh,
                                                       float* __restrict__ p0,
                                                       float* __restrict__ p7) {
    int j0 = blockIdx.x * 64;
    int kc = blockIdx.y;
    int kbase = kc * 320;
    int tid = threadIdx.x;
    int wave = tid >> 6, lane = tid & 63;
    int lan = lane & 15, lk = lane >> 4;

    __shared__ s16x8 Xl[2560];   // 40 KB: slot b*40 + (koct&~7) + ((koct&7)^(b&7))

    // stage X-slice once: thread handles b = tid>>2, koct = (tid&3)*10 + it
    {
        int b = tid >> 2;
#pragma unroll
        for (int it = 0; it < 10; ++it) {
            int koct = (tid & 3) * 10 + it;
            int kabs = kbase + koct * 8;
            const float* src;
            if (kabs < 512)       src = emb + (size_t)b * 512 + kabs;
            else if (kabs < 1536) src = ctx + (size_t)b * 1024 + (kabs - 512);
            else                  src = h   + (size_t)b * 1024 + (kabs - 1536);
            float4 f0 = *(const float4*)src;
            float4 f1 = *(const float4*)(src + 4);
            s16x8 pk;
            pk[0] = (short)f2bf(f0.x); pk[1] = (short)f2bf(f0.y);
            pk[2] = (short)f2bf(f0.z); pk[3] = (short)f2bf(f0.w);
            pk[4] = (short)f2bf(f1.x); pk[5] = (short)f2bf(f1.y);
            pk[6] = (short)f2bf(f1.z); pk[7] = (short)f2bf(f1.w);
            Xl[b * 40 + (koct & ~7) + ((koct & 7) ^ (b & 7))] = pk;
        }
    }
    __syncthreads();

    int jrow = j0 + wave * 16 + lan;
    auto wptr = [&](int t) -> const float* {
        int kabs = kbase + t * 32;
        return (kabs < 1536) ? (Wih + (size_t)jrow * 1536 + kabs + lk * 8)
                             : (Whh + (size_t)jrow * 1024 + (kabs - 1536) + lk * 8);
    };

    f32x4 acc[4];
#pragma unroll
    for (int ni = 0; ni < 4; ++ni) acc[ni] = (f32x4){0.f, 0.f, 0.f, 0.f};

    // depth-2 W prefetch
    const float* q0 = wptr(0);
    const float* q1 = wptr(1);
    float4 pa0 = *(const float4*)q0, pa1 = *(const float4*)(q0 + 4);
    float4 pb0 = *(const float4*)q1, pb1 = *(const float4*)(q1 + 4);

    for (int t = 0; t < 10; ++t) {
        float4 pc0 = {0.f, 0.f, 0.f, 0.f}, pc1 = {0.f, 0.f, 0.f, 0.f};
        if (t < 8) {
            const float* q = wptr(t + 2);
            pc0 = *(const float4*)q; pc1 = *(const float4*)(q + 4);
        }
        s16x8 af;
        af[0] = (short)f2bf(pa0.x); af[1] = (short)f2bf(pa0.y);
        af[2] = (short)f2bf(pa0.z); af[3] = (short)f2bf(pa0.w);
        af[4] = (short)f2bf(pa1.x); af[5] = (short)f2bf(pa1.y);
        af[6] = (short)f2bf(pa1.z); af[7] = (short)f2bf(pa1.w);
        int koct = t * 4 + lk;
        int kg = koct & ~7, ks = koct & 7;
#pragma unroll
        for (int ni = 0; ni < 4; ++ni) {
            int b = ni * 16 + lan;
            s16x8 bf = Xl[b * 40 + kg + (ks ^ (b & 7))];
            acc[ni] = __builtin_amdgcn_mfma_f32_16x16x32_bf16(af, bf, acc[ni], 0, 0, 0);
        }
        pa0 = pb0; pa1 = pb1; pb0 = pc0; pb1 = pc1;
    }

    float* dst = (kc < 7) ? (p0 + (size_t)kc * 262144) : p7;
#pragma unroll
    for (int ni = 0; ni < 4; ++ni) {
        int b = ni * 16 + lan;
#pragma unroll
        for (int r = 0; r < 4; ++r) {
            int j = j0 + wave * 16 + lk * 4 + r;
            dst[(size_t)b * 4096 + j] = acc[ni][r];
        }
    }
}

// ---------------------------------------------------------------------------
// 5. LSTM elementwise + 8-way partial reduce
__global__ __launch_bounds__(256) void k_lstm(const float* __restrict__ p0,
                                              const float* __restrict__ p7,
                                              const float* __restrict__ bih,
                                              const float* __restrict__ bhh,
                                              const float* __restrict__ c0,
                                              float* __restrict__ out_h,
                                              float* __restrict__ out_c) {
    int idx = blockIdx.x * 256 + threadIdx.x;
    int b = idx >> 10, hh = idx & 1023;
    float g[4];
#pragma unroll
    for (int gt = 0; gt < 4; ++gt) {
        size_t off = (size_t)b * 4096 + gt * 1024 + hh;
        float s = p7[off] + bih[gt * 1024 + hh] + bhh[gt * 1024 + hh];
#pragma unroll
        for (int kc = 0; kc < 7; ++kc) s += p0[(size_t)kc * 262144 + off];
        g[gt] = s;
    }
    float c_old = c0[idx];
    float nc = sigmoidf_(g[1]) * c_old + sigmoidf_(g[0]) * tanhf(g[2]);
    float nh = sigmoidf_(g[3]) * tanhf(nc);
    out_h[idx] = nh;
    out_c[idx] = nc;
}

// ---------------------------------------------------------------------------
// 6a. readout partials: grid (32 j-tiles of 16, 16 K-chunks of 160).
__global__ __launch_bounds__(256) void k_readout_part(const float* __restrict__ nh,
                                                      const float* __restrict__ ctx,
                                                      const float* __restrict__ emb,
                                                      const float* __restrict__ Wo,
                                                      float* __restrict__ Tp) {
    int j0 = blockIdx.x * 16;
    int kc = blockIdx.y;
    __shared__ float Xs[64][33];
    __shared__ float Ws[16][33];
    int tid = threadIdx.x;
    int b = tid & 63, jg = tid >> 6;
    float acc[4] = {0.f, 0.f, 0.f, 0.f};

    for (int k0 = kc * 160; k0 < kc * 160 + 160; k0 += 32) {
        const float* xsrc; int xstride, xoff;
        if (k0 < 1024)      { xsrc = nh;  xstride = 1024; xoff = k0; }
        else if (k0 < 2048) { xsrc = ctx; xstride = 1024; xoff = k0 - 1024; }
        else                { xsrc = emb; xstride = 512;  xoff = k0 - 2048; }
        __syncthreads();
#pragma unroll
        for (int i = 0; i < 8; ++i) {
            int idx = tid + i * 256;
            int kk = idx & 31, bb = idx >> 5;
            Xs[bb][kk] = xsrc[(size_t)bb * xstride + xoff + kk];
        }
#pragma unroll
        for (int i = 0; i < 2; ++i) {
            int idx = tid + i * 256;
            int kk = idx & 31, jj = idx >> 5;
            Ws[jj][kk] = Wo[(size_t)(j0 + jj) * 2560 + k0 + kk];
        }
        __syncthreads();
#pragma unroll
        for (int kk = 0; kk < 32; ++kk) {
            float x = Xs[b][kk];
            acc[0] += x * Ws[jg * 4 + 0][kk];
            acc[1] += x * Ws[jg * 4 + 1][kk];
            acc[2] += x * Ws[jg * 4 + 2][kk];
            acc[3] += x * Ws[jg * 4 + 3][kk];
        }
    }
#pragma unroll
    for (int c = 0; c < 4; ++c)
        Tp[((size_t)kc * 64 + b) * 512 + j0 + jg * 4 + c] = acc[c];
}

// 6b. readout finish: T = tanh(sum 16 partials + bias)
__global__ __launch_bounds__(256) void k_readout_fin(const float* __restrict__ Tp,
                                                     const float* __restrict__ bo,
                                                     float* __restrict__ T) {
    int i = blockIdx.x * 256 + threadIdx.x;
    int j = i & 511;
    float s = 0.f;
#pragma unroll
    for (int kc = 0; kc < 16; ++kc) s += Tp[(size_t)kc * 32768 + i];
    T[i] = tanhf(s + bo[j]);
}

// ---------------------------------------------------------------------------
// 7. logits via MFMA, barrier-free main loop. grid 500 x 256 thr (4 waves).
__global__ __launch_bounds__(256, 2) void k_logits(const float* __restrict__ T,
                                                   const float* __restrict__ table,
                                                   float* __restrict__ out) {
    int tid = threadIdx.x;
    int wave = tid >> 6, lane = tid & 63;
    int lan = lane & 15, lk = lane >> 4;

    __shared__ s16x8 Tl[4096];   // 64 KB: slot b*64 + (koct ^ (b&7)), koct 0..63

#pragma unroll
    for (int it = 0; it < 16; ++it) {
        int idx = tid + it * 256;
        int b = idx >> 6, koct = idx & 63;
        const float* src = T + (size_t)b * 512 + koct * 8;
        float4 f0 = *(const float4*)src;
        float4 f1 = *(const float4*)(src + 4);
        s16x8 pk;
        pk[0] = (short)f2bf(f0.x); pk[1] = (short)f2bf(f0.y);
        pk[2] = (short)f2bf(f0.z); pk[3] = (short)f2bf(f0.w);
        pk[4] = (short)f2bf(f1.x); pk[5] = (short)f2bf(f1.y);
        pk[6] = (short)f2bf(f1.z); pk[7] = (short)f2bf(f1.w);
        Tl[b * 64 + (koct ^ (b & 7))] = pk;
    }
    __syncthreads();

    int v0 = blockIdx.x * 64 + wave * 16;
    const float* tabRow = table + (size_t)(v0 + lan) * 512 + lk * 8;

    f32x4 acc[4];
#pragma unroll
    for (int ni = 0; ni < 4; ++ni) acc[ni] = (f32x4){0.f, 0.f, 0.f, 0.f};

    float4 pa0 = *(const float4*)(tabRow);
    float4 pa1 = *(const float4*)(tabRow + 4);
    float4 pb0 = *(const float4*)(tabRow + 32);
    float4 pb1 = *(const float4*)(tabRow + 36);

    for (int t = 0; t < 16; ++t) {
        float4 pc0 = {0.f, 0.f, 0.f, 0.f}, pc1 = {0.f, 0.f, 0.f, 0.f};
        if (t < 14) {
            pc0 = *(const float4*)(tabRow + (t + 2) * 32);
            pc1 = *(const float4*)(tabRow + (t + 2) * 32 + 4);
        }
        s16x8 af;
        af[0] = (short)f2bf(pa0.x); af[1] = (short)f2bf(pa0.y);
        af[2] = (short)f2bf(pa0.z); af[3] = (short)f2bf(pa0.w);
        af[4] = (short)f2bf(pa1.x); af[5] = (short)f2bf(pa1.y);
        af[6] = (short)f2bf(pa1.z); af[7] = (short)f2bf(pa1.w);
        int akoct = t * 4 + lk;
#pragma unroll
        for (int ni = 0; ni < 4; ++ni) {
            int bg = ni * 16 + lan;
            s16x8 bf = Tl[bg * 64 + (akoct ^ (bg & 7))];
            acc[ni] = __builtin_amdgcn_mfma_f32_16x16x32_bf16(af, bf, acc[ni], 0, 0, 0);
        }
        pa0 = pb0; pa1 = pb1; pb0 = pc0; pb1 = pc1;
    }

#pragma unroll
    for (int ni = 0; ni < 4; ++ni) {
        int bg = ni * 16 + lan;
        float4 o;
        o.x = acc[ni][0]; o.y = acc[ni][1]; o.z = acc[ni][2]; o.w = acc[ni][3];
        *(float4*)(out + (size_t)bg * 32000 + v0 + lk * 4) = o;
    }
}

// ---------------------------------------------------------------------------
extern "C" void kernel_launch(void* const* d_in, const int* in_sizes, int n_in,
                              void* d_out, int out_size, void* d_ws, size_t ws_size,
                              hipStream_t stream) {
    const int*      tok   = (const int*)d_in[0];
    const float*    h0    = (const float*)d_in[1];
    const float*    c0    = (const float*)d_in[2];
    const float*    enc   = (const float*)d_in[3];
    const unsigned* mask  = (const unsigned*)d_in[4];
    const float*    table = (const float*)d_in[5];
    const float*    We    = (const float*)d_in[6];
    const float*    Wd    = (const float*)d_in[7];
    const float*    va    = (const float*)d_in[8];
    const float*    Wih   = (const float*)d_in[9];
    const float*    Whh   = (const float*)d_in[10];
    const float*    bih   = (const float*)d_in[11];
    const float*    bhh   = (const float*)d_in[12];
    const float*    Wo    = (const float*)d_in[13];
    const float*    bo    = (const float*)d_in[14];

    float* out    = (float*)d_out;
    float* logits = out;                      // 64*32000 = 2048000
    float* out_h  = out + 2048000;            // 65536
    float* out_c  = out + 2048000 + 65536;    // 65536
    float* out_w  = out + 2048000 + 131072;   // 32768

    float* ws     = (float*)d_ws;
    float* emb    = ws;             // 32768
    float* dp     = ws + 32768;     // 16384
    float* scores = ws + 49152;     // 32768
    float* ctx    = ws + 81920;     // 65536
    float* big    = ws + 147456;    // 524288 floats (gates p7 / readout Tp)
    float* T      = ws + 671744;    // 32768
    ushort* Wbf   = (ushort*)(ws + 704512);   // 262144 bf16 (131072 float-slots)
    float* stats  = ws + 835584;    // 2048

    float* ctxp     = logits;       // 64*16*1024 = 1M floats, consumed by k_ctx_fin
    float* gates_p0 = logits;       // kc 0..6 partials (after ctxp consumed)
    float* gates_p7 = big;          // kc 7 partial
    float* Tp       = big;          // readout partials (after k_lstm consumed gates)

    k_prep        <<<384, 256, 0, stream>>>(tok, table, We, h0, Wd, emb, Wbf, dp);
    k_scores_ctx  <<<1024, 256, 0, stream>>>(enc, Wbf, dp, va, mask, scores, stats, ctxp);
    k_ctx_fin     <<<64, 256, 0, stream>>>(stats, scores, ctxp, out_w, ctx);
    k_gates_mfma  <<<dim3(64, 8), 256, 0, stream>>>(emb, ctx, h0, Wih, Whh, gates_p0, gates_p7);
    k_lstm        <<<256, 256, 0, stream>>>(gates_p0, gates_p7, bih, bhh, c0, out_h, out_c);
    k_readout_part<<<dim3(32, 16), 256, 0, stream>>>(out_h, ctx, emb, Wo, Tp);
    k_readout_fin <<<128, 256, 0, stream>>>(Tp, bo, T);
    k_logits      <<<500, 256, 0, stream>>>(T, table, logits);
}

// Round 17
// 130.298 us; speedup vs baseline: 1.4649x; 1.1495x over previous
//
#include <hip/hip_runtime.h>
#include <hip/hip_bf16.h>
#include <math.h>

// B=64, S=512, VOCAB=32000, EMBED=512, HIDDEN=1024, ENC=1024, ATTN=256

typedef float f32x4 __attribute__((ext_vector_type(4)));
typedef short s16x8 __attribute__((ext_vector_type(8)));

__device__ __forceinline__ float sigmoidf_(float x) { return 1.0f / (1.0f + expf(-x)); }

__device__ __forceinline__ ushort f2bf(float f) {
    __hip_bfloat16 h = __float2bfloat16(f);
    return *reinterpret_cast<ushort*>(&h);
}

// ---------------------------------------------------------------------------
// 1. prep: blocks 0..63 embed gather | 64..319 We->bf16 | 320..383 dec_proj
__global__ __launch_bounds__(256) void k_prep(const int* __restrict__ tok,
                                              const float* __restrict__ table,
                                              const float* __restrict__ We,
                                              const float* __restrict__ h0,
                                              const float* __restrict__ Wd,
                                              float* __restrict__ emb,
                                              ushort* __restrict__ Wbf,
                                              float* __restrict__ dp) {
    __shared__ float sh[1024];
    int bx = blockIdx.x;
    int tid = threadIdx.x;
    if (bx < 64) {
        int b = bx;
        int t = tok[b];
        const float4* src = (const float4*)(table + (size_t)t * 512);
        float4* dst = (float4*)(emb + (size_t)b * 512);
        if (tid < 128) dst[tid] = src[tid];
    } else if (bx < 320) {
        int i = (bx - 64) * 256 + tid;
        float4 f = ((const float4*)We)[i];
        ushort4 o;
        o.x = f2bf(f.x); o.y = f2bf(f.y); o.z = f2bf(f.z); o.w = f2bf(f.w);
        ((ushort4*)Wbf)[i] = o;
    } else {
        int b = bx - 320;
        int a = tid;
        for (int i = tid; i < 1024; i += 256) sh[i] = h0[(size_t)b * 1024 + i];
        __syncthreads();
        const float* w = Wd + (size_t)a * 1024;
        float acc = 0.f;
#pragma unroll 4
        for (int k = 0; k < 1024; k += 4) {
            float4 w4 = *(const float4*)(w + k);
            float4 h4 = *(const float4*)(sh + k);
            acc += w4.x * h4.x + w4.y * h4.y + w4.z * h4.z + w4.w * h4.w;
        }
        dp[b * 256 + a] = acc;
    }
}

// ---------------------------------------------------------------------------
// 2. fused scores (MFMA) + mask + chunk softmax + partial context.
//    [r14 best-measured: 82.7us] r10 geometry: grid 1024 = (b, 16 s-chunks
//    of 32), 4 blocks/CU, wave tile 32x64 (2rf x 4ni), XOR-swizzled LDS,
//    T14 register double-buffer staging.
__global__ __launch_bounds__(256, 4) void k_scores_ctx(const float* __restrict__ enc,
                                                       const ushort* __restrict__ Wbf,
                                                       const float* __restrict__ dp,
                                                       const float* __restrict__ v,
                                                       const unsigned* __restrict__ mask,
                                                       float* __restrict__ scores,
                                                       float* __restrict__ stats,
                                                       float* __restrict__ ctxp) {
    int b  = blockIdx.x >> 4;
    int sc = blockIdx.x & 15;
    int s0 = sc << 5;
    int tid = threadIdx.x;
    int wave = tid >> 6, lane = tid & 63;
    int lan = lane & 15, lk = lane >> 4;

    __shared__ s16x8 Al[256];    // 4 KB : 32 rows x 8 koct, slot row*8+(koct^(row&7))
    __shared__ s16x8 Bl[2048];   // 32 KB: 256 a  x 8 koct, slot a*8+(koct^(a&7))
    __shared__ float sdp[256], sv[256];
    __shared__ float wpart[4][32];
    __shared__ float ps[32];
    __shared__ int flag;

    sdp[tid] = dp[b * 256 + tid];
    sv[tid]  = v[tid];
    int bad = 0;
    for (int i = tid; i < 512; i += 256)
        if (mask[i] > 1u) bad = 1;
    if (tid == 0) flag = 0;
    __syncthreads();
    if (bad) atomicOr(&flag, 1);

    const float* encB = enc + ((size_t)(b * 512 + s0)) * 1024;

    int arow = tid >> 3, akoct8 = tid & 7;            // A: 1 slot/thread
    const float* aSrcBase = encB + (size_t)arow * 1024 + akoct8 * 8;

    f32x4 acc[2][4];
#pragma unroll
    for (int rf = 0; rf < 2; ++rf)
#pragma unroll
        for (int ni = 0; ni < 4; ++ni) acc[rf][ni] = (f32x4){0.f, 0.f, 0.f, 0.f};

    float4 rA0, rA1;
    s16x8 rB[8];

    rA0 = *(const float4*)(aSrcBase);
    rA1 = *(const float4*)(aSrcBase + 4);
#pragma unroll
    for (int it = 0; it < 8; ++it) {
        int idx = tid + it * 256;
        int a = idx >> 3, koct = idx & 7;
        rB[it] = *(const s16x8*)(Wbf + (size_t)a * 1024 + 0 + koct * 8);
    }

    for (int t = 0; t < 16; ++t) {
        __syncthreads();
        {
            s16x8 pk;
            pk[0] = (short)f2bf(rA0.x); pk[1] = (short)f2bf(rA0.y);
            pk[2] = (short)f2bf(rA0.z); pk[3] = (short)f2bf(rA0.w);
            pk[4] = (short)f2bf(rA1.x); pk[5] = (short)f2bf(rA1.y);
            pk[6] = (short)f2bf(rA1.z); pk[7] = (short)f2bf(rA1.w);
            Al[arow * 8 + (akoct8 ^ (arow & 7))] = pk;
        }
#pragma unroll
        for (int it = 0; it < 8; ++it) {
            int idx = tid + it * 256;
            int a = idx >> 3, koct = idx & 7;
            Bl[a * 8 + (koct ^ (a & 7))] = rB[it];
        }
        if (t < 15) {
            int k1 = (t + 1) * 64;
            rA0 = *(const float4*)(aSrcBase + k1);
            rA1 = *(const float4*)(aSrcBase + k1 + 4);
#pragma unroll
            for (int it = 0; it < 8; ++it) {
                int idx = tid + it * 256;
                int a = idx >> 3, koct = idx & 7;
                rB[it] = *(const s16x8*)(Wbf + (size_t)a * 1024 + k1 + koct * 8);
            }
        }
        __syncthreads();
#pragma unroll
        for (int ks = 0; ks < 2; ++ks) {
            int akoct = ks * 4 + lk;
            s16x8 af[2];
#pragma unroll
            for (int rf = 0; rf < 2; ++rf) {
                int row = rf * 16 + lan;
                af[rf] = Al[row * 8 + (akoct ^ (row & 7))];
            }
#pragma unroll
            for (int ni = 0; ni < 4; ++ni) {
                int a = wave * 64 + ni * 16 + lan;
                s16x8 bf = Bl[a * 8 + (akoct ^ (a & 7))];
#pragma unroll
                for (int rf = 0; rf < 2; ++rf)
                    acc[rf][ni] = __builtin_amdgcn_mfma_f32_16x16x32_bf16(af[rf], bf, acc[rf][ni], 0, 0, 0);
            }
        }
    }

    float rs[2][4];
#pragma unroll
    for (int rf = 0; rf < 2; ++rf)
#pragma unroll
        for (int r = 0; r < 4; ++r) rs[rf][r] = 0.f;
#pragma unroll
    for (int rf = 0; rf < 2; ++rf) {
#pragma unroll
        for (int ni = 0; ni < 4; ++ni) {
            int a = wave * 64 + ni * 16 + lan;
            float dpv = sdp[a], vv = sv[a];
#pragma unroll
            for (int r = 0; r < 4; ++r) {
                float x = acc[rf][ni][r] + dpv;
                float th = 1.f - 2.f / (1.f + __expf(2.f * x));
                rs[rf][r] += th * vv;
            }
        }
    }
#pragma unroll
    for (int off = 1; off < 16; off <<= 1) {
#pragma unroll
        for (int rf = 0; rf < 2; ++rf)
#pragma unroll
            for (int r = 0; r < 4; ++r) rs[rf][r] += __shfl_xor(rs[rf][r], off);
    }
    if (lan == 0) {
#pragma unroll
        for (int rf = 0; rf < 2; ++rf)
#pragma unroll
            for (int r = 0; r < 4; ++r)
                wpart[wave][rf * 16 + lk * 4 + r] = rs[rf][r];
    }
    __syncthreads();

    bool u8 = (flag != 0);
    if (tid < 32) {
        int s = s0 + tid;
        float val = wpart[0][tid] + wpart[1][tid] + wpart[2][tid] + wpart[3][tid];
        bool m = u8 ? (((const unsigned char*)mask)[(size_t)b * 512 + s] != 0)
                    : (mask[(size_t)b * 512 + s] != 0u);
        val = m ? val : -1e9f;
        scores[(size_t)b * 512 + s] = val;
        float mx = val;
#pragma unroll
        for (int off = 1; off < 32; off <<= 1) mx = fmaxf(mx, __shfl_xor(mx, off));
        float e = __expf(val - mx);
        float sum = e;
#pragma unroll
        for (int off = 1; off < 32; off <<= 1) sum += __shfl_xor(sum, off);
        ps[tid] = e;
        if (tid == 0) {
            stats[((size_t)b * 16 + sc) * 2]     = mx;
            stats[((size_t)b * 16 + sc) * 2 + 1] = sum;
        }
    }
    __syncthreads();

    f32x4 cacc = (f32x4){0.f, 0.f, 0.f, 0.f};
    const float* eb = encB + tid * 4;
#pragma unroll 8
    for (int s = 0; s < 32; ++s) {
        f32x4 ev = *(const f32x4*)(eb + (size_t)s * 1024);
        float pv = ps[s];
        cacc += pv * ev;
    }
    *(f32x4*)(ctxp + ((size_t)(b * 16 + sc)) * 1024 + tid * 4) = cacc;
}

// ---------------------------------------------------------------------------
// 3. combine 16 chunk partials -> ctx, out_w. grid 64 (one block per b).
__global__ __launch_bounds__(256) void k_ctx_fin(const float* __restrict__ stats,
                                                 const float* __restrict__ scores,
                                                 const float* __restrict__ ctxp,
                                                 float* __restrict__ out_w,
                                                 float* __restrict__ ctx) {
    int b = blockIdx.x;
    int tid = threadIdx.x;
    __shared__ float sm[16], ssum[16];
    if (tid < 16) {
        sm[tid]   = stats[((size_t)b * 16 + tid) * 2];
        ssum[tid] = stats[((size_t)b * 16 + tid) * 2 + 1];
    }
    __syncthreads();
    float M = sm[0];
#pragma unroll
    for (int i = 1; i < 16; ++i) M = fmaxf(M, sm[i]);
    float total = 0.f;
#pragma unroll
    for (int i = 0; i < 16; ++i) total += ssum[i] * __expf(sm[i] - M);
    float inv = 1.f / total;

    out_w[(size_t)b * 512 + tid]       = __expf(scores[(size_t)b * 512 + tid] - M) * inv;
    out_w[(size_t)b * 512 + tid + 256] = __expf(scores[(size_t)b * 512 + tid + 256] - M) * inv;

    f32x4 acc = (f32x4){0.f, 0.f, 0.f, 0.f};
#pragma unroll
    for (int sc = 0; sc < 16; ++sc) {
        float w = __expf(sm[sc] - M) * inv;
        f32x4 p = *(const f32x4*)(ctxp + ((size_t)(b * 16 + sc)) * 1024 + tid * 4);
        acc += w * p;
    }
    *(f32x4*)(ctx + (size_t)b * 1024 + tid * 4) = acc;
}

// ---------------------------------------------------------------------------
// 4. gates via MFMA, barrier-free W stream. grid (64 j-tiles of 64, 8 kc of
//    320). X-slice staged once (swizzled bf16, 40 KB); W rows streamed.
__global__ __launch_bounds__(256, 2) void k_gates_mfma(const float* __restrict__ emb,
                                                       const float* __restrict__ ctx,
                                                       const float* __restrict__ h,
                                                       const float* __restrict__ Wih,
                                                       const float* __restrict__ Whh,
                                                       float* __restrict__ p0,
                                                       float* __restrict__ p7) {
    int j0 = blockIdx.x * 64;
    int kc = blockIdx.y;
    int kbase = kc * 320;
    int tid = threadIdx.x;
    int wave = tid >> 6, lane = tid & 63;
    int lan = lane & 15, lk = lane >> 4;

    __shared__ s16x8 Xl[2560];   // 40 KB: slot b*40 + (koct&~7) + ((koct&7)^(b&7))

    {
        int b = tid >> 2;
#pragma unroll
        for (int it = 0; it < 10; ++it) {
            int koct = (tid & 3) * 10 + it;
            int kabs = kbase + koct * 8;
            const float* src;
            if (kabs < 512)       src = emb + (size_t)b * 512 + kabs;
            else if (kabs < 1536) src = ctx + (size_t)b * 1024 + (kabs - 512);
            else                  src = h   + (size_t)b * 1024 + (kabs - 1536);
            float4 f0 = *(const float4*)src;
            float4 f1 = *(const float4*)(src + 4);
            s16x8 pk;
            pk[0] = (short)f2bf(f0.x); pk[1] = (short)f2bf(f0.y);
            pk[2] = (short)f2bf(f0.z); pk[3] = (short)f2bf(f0.w);
            pk[4] = (short)f2bf(f1.x); pk[5] = (short)f2bf(f1.y);
            pk[6] = (short)f2bf(f1.z); pk[7] = (short)f2bf(f1.w);
            Xl[b * 40 + (koct & ~7) + ((koct & 7) ^ (b & 7))] = pk;
        }
    }
    __syncthreads();

    int jrow = j0 + wave * 16 + lan;
    auto wptr = [&](int t) -> const float* {
        int kabs = kbase + t * 32;
        return (kabs < 1536) ? (Wih + (size_t)jrow * 1536 + kabs + lk * 8)
                             : (Whh + (size_t)jrow * 1024 + (kabs - 1536) + lk * 8);
    };

    f32x4 acc[4];
#pragma unroll
    for (int ni = 0; ni < 4; ++ni) acc[ni] = (f32x4){0.f, 0.f, 0.f, 0.f};

    const float* q0 = wptr(0);
    const float* q1 = wptr(1);
    float4 pa0 = *(const float4*)q0, pa1 = *(const float4*)(q0 + 4);
    float4 pb0 = *(const float4*)q1, pb1 = *(const float4*)(q1 + 4);

    for (int t = 0; t < 10; ++t) {
        float4 pc0 = {0.f, 0.f, 0.f, 0.f}, pc1 = {0.f, 0.f, 0.f, 0.f};
        if (t < 8) {
            const float* q = wptr(t + 2);
            pc0 = *(const float4*)q; pc1 = *(const float4*)(q + 4);
        }
        s16x8 af;
        af[0] = (short)f2bf(pa0.x); af[1] = (short)f2bf(pa0.y);
        af[2] = (short)f2bf(pa0.z); af[3] = (short)f2bf(pa0.w);
        af[4] = (short)f2bf(pa1.x); af[5] = (short)f2bf(pa1.y);
        af[6] = (short)f2bf(pa1.z); af[7] = (short)f2bf(pa1.w);
        int koct = t * 4 + lk;
        int kg = koct & ~7, ks = koct & 7;
#pragma unroll
        for (int ni = 0; ni < 4; ++ni) {
            int b = ni * 16 + lan;
            s16x8 bf = Xl[b * 40 + kg + (ks ^ (b & 7))];
            acc[ni] = __builtin_amdgcn_mfma_f32_16x16x32_bf16(af, bf, acc[ni], 0, 0, 0);
        }
        pa0 = pb0; pa1 = pb1; pb0 = pc0; pb1 = pc1;
    }

    float* dst = (kc < 7) ? (p0 + (size_t)kc * 262144) : p7;
#pragma unroll
    for (int ni = 0; ni < 4; ++ni) {
        int b = ni * 16 + lan;
#pragma unroll
        for (int r = 0; r < 4; ++r) {
            int j = j0 + wave * 16 + lk * 4 + r;
            dst[(size_t)b * 4096 + j] = acc[ni][r];
        }
    }
}

// ---------------------------------------------------------------------------
// 5. LSTM elementwise + 8-way partial reduce
__global__ __launch_bounds__(256) void k_lstm(const float* __restrict__ p0,
                                              const float* __restrict__ p7,
                                              const float* __restrict__ bih,
                                              const float* __restrict__ bhh,
                                              const float* __restrict__ c0,
                                              float* __restrict__ out_h,
                                              float* __restrict__ out_c) {
    int idx = blockIdx.x * 256 + threadIdx.x;
    int b = idx >> 10, hh = idx & 1023;
    float g[4];
#pragma unroll
    for (int gt = 0; gt < 4; ++gt) {
        size_t off = (size_t)b * 4096 + gt * 1024 + hh;
        float s = p7[off] + bih[gt * 1024 + hh] + bhh[gt * 1024 + hh];
#pragma unroll
        for (int kc = 0; kc < 7; ++kc) s += p0[(size_t)kc * 262144 + off];
        g[gt] = s;
    }
    float c_old = c0[idx];
    float nc = sigmoidf_(g[1]) * c_old + sigmoidf_(g[0]) * tanhf(g[2]);
    float nh = sigmoidf_(g[3]) * tanhf(nc);
    out_h[idx] = nh;
    out_c[idx] = nc;
}

// ---------------------------------------------------------------------------
// 6a. readout via MFMA, barrier-free Wo stream (gates template). grid (8
//     j-tiles of 64, 16 kc of 160). X-slice [64b x 160k] staged once as
//     swizzled bf16 (24.5 KB, rows padded to 24 octs so the XOR group is
//     bijective); Wo rows streamed per-wave with depth-2 prefetch.
__global__ __launch_bounds__(256, 2) void k_readout_mfma(const float* __restrict__ nh,
                                                         const float* __restrict__ ctx,
                                                         const float* __restrict__ emb,
                                                         const float* __restrict__ Wo,
                                                         float* __restrict__ Tp) {
    int j0 = blockIdx.x * 64;
    int kc = blockIdx.y;
    int kbase = kc * 160;
    int tid = threadIdx.x;
    int wave = tid >> 6, lane = tid & 63;
    int lan = lane & 15, lk = lane >> 4;

    __shared__ s16x8 Xl[1536];   // 24 KB: slot b*24 + (koct&~7) + ((koct&7)^(b&7)), koct 0..19

    {
        int b = tid >> 2;
#pragma unroll
        for (int it = 0; it < 5; ++it) {
            int koct = (tid & 3) * 5 + it;           // 0..19
            int kabs = kbase + koct * 8;
            const float* src;
            if (kabs < 1024)      src = nh  + (size_t)b * 1024 + kabs;
            else if (kabs < 2048) src = ctx + (size_t)b * 1024 + (kabs - 1024);
            else                  src = emb + (size_t)b * 512  + (kabs - 2048);
            float4 f0 = *(const float4*)src;
            float4 f1 = *(const float4*)(src + 4);
            s16x8 pk;
            pk[0] = (short)f2bf(f0.x); pk[1] = (short)f2bf(f0.y);
            pk[2] = (short)f2bf(f0.z); pk[3] = (short)f2bf(f0.w);
            pk[4] = (short)f2bf(f1.x); pk[5] = (short)f2bf(f1.y);
            pk[6] = (short)f2bf(f1.z); pk[7] = (short)f2bf(f1.w);
            Xl[b * 24 + (koct & ~7) + ((koct & 7) ^ (b & 7))] = pk;
        }
    }
    __syncthreads();

    int jrow = j0 + wave * 16 + lan;
    const float* wBase = Wo + (size_t)jrow * 2560 + kbase + lk * 8;

    f32x4 acc[4];
#pragma unroll
    for (int ni = 0; ni < 4; ++ni) acc[ni] = (f32x4){0.f, 0.f, 0.f, 0.f};

    float4 pa0 = *(const float4*)(wBase);
    float4 pa1 = *(const float4*)(wBase + 4);
    float4 pb0 = *(const float4*)(wBase + 32);
    float4 pb1 = *(const float4*)(wBase + 36);

    for (int t = 0; t < 5; ++t) {
        float4 pc0 = {0.f, 0.f, 0.f, 0.f}, pc1 = {0.f, 0.f, 0.f, 0.f};
        if (t < 3) {
            pc0 = *(const float4*)(wBase + (t + 2) * 32);
            pc1 = *(const float4*)(wBase + (t + 2) * 32 + 4);
        }
        s16x8 af;
        af[0] = (short)f2bf(pa0.x); af[1] = (short)f2bf(pa0.y);
        af[2] = (short)f2bf(pa0.z); af[3] = (short)f2bf(pa0.w);
        af[4] = (short)f2bf(pa1.x); af[5] = (short)f2bf(pa1.y);
        af[6] = (short)f2bf(pa1.z); af[7] = (short)f2bf(pa1.w);
        int koct = t * 4 + lk;
        int kg = koct & ~7, ks = koct & 7;
#pragma unroll
        for (int ni = 0; ni < 4; ++ni) {
            int b = ni * 16 + lan;
            s16x8 bf = Xl[b * 24 + kg + (ks ^ (b & 7))];
            acc[ni] = __builtin_amdgcn_mfma_f32_16x16x32_bf16(af, bf, acc[ni], 0, 0, 0);
        }
        pa0 = pb0; pa1 = pb1; pb0 = pc0; pb1 = pc1;
    }

#pragma unroll
    for (int ni = 0; ni < 4; ++ni) {
        int b = ni * 16 + lan;
#pragma unroll
        for (int r = 0; r < 4; ++r) {
            int j = j0 + wave * 16 + lk * 4 + r;
            Tp[(size_t)kc * 32768 + (size_t)b * 512 + j] = acc[ni][r];
        }
    }
}

// 6b. readout finish: T = tanh(sum 16 partials + bias)
__global__ __launch_bounds__(256) void k_readout_fin(const float* __restrict__ Tp,
                                                     const float* __restrict__ bo,
                                                     float* __restrict__ T) {
    int i = blockIdx.x * 256 + threadIdx.x;
    int j = i & 511;
    float s = 0.f;
#pragma unroll
    for (int kc = 0; kc < 16; ++kc) s += Tp[(size_t)kc * 32768 + i];
    T[i] = tanhf(s + bo[j]);
}

// ---------------------------------------------------------------------------
// 7. logits via MFMA, barrier-free main loop. grid 500 x 256 thr (4 waves).
__global__ __launch_bounds__(256, 2) void k_logits(const float* __restrict__ T,
                                                   const float* __restrict__ table,
                                                   float* __restrict__ out) {
    int tid = threadIdx.x;
    int wave = tid >> 6, lane = tid & 63;
    int lan = lane & 15, lk = lane >> 4;

    __shared__ s16x8 Tl[4096];   // 64 KB: slot b*64 + (koct ^ (b&7)), koct 0..63

#pragma unroll
    for (int it = 0; it < 16; ++it) {
        int idx = tid + it * 256;
        int b = idx >> 6, koct = idx & 63;
        const float* src = T + (size_t)b * 512 + koct * 8;
        float4 f0 = *(const float4*)src;
        float4 f1 = *(const float4*)(src + 4);
        s16x8 pk;
        pk[0] = (short)f2bf(f0.x); pk[1] = (short)f2bf(f0.y);
        pk[2] = (short)f2bf(f0.z); pk[3] = (short)f2bf(f0.w);
        pk[4] = (short)f2bf(f1.x); pk[5] = (short)f2bf(f1.y);
        pk[6] = (short)f2bf(f1.z); pk[7] = (short)f2bf(f1.w);
        Tl[b * 64 + (koct ^ (b & 7))] = pk;
    }
    __syncthreads();

    int v0 = blockIdx.x * 64 + wave * 16;
    const float* tabRow = table + (size_t)(v0 + lan) * 512 + lk * 8;

    f32x4 acc[4];
#pragma unroll
    for (int ni = 0; ni < 4; ++ni) acc[ni] = (f32x4){0.f, 0.f, 0.f, 0.f};

    float4 pa0 = *(const float4*)(tabRow);
    float4 pa1 = *(const float4*)(tabRow + 4);
    float4 pb0 = *(const float4*)(tabRow + 32);
    float4 pb1 = *(const float4*)(tabRow + 36);

    for (int t = 0; t < 16; ++t) {
        float4 pc0 = {0.f, 0.f, 0.f, 0.f}, pc1 = {0.f, 0.f, 0.f, 0.f};
        if (t < 14) {
            pc0 = *(const float4*)(tabRow + (t + 2) * 32);
            pc1 = *(const float4*)(tabRow + (t + 2) * 32 + 4);
        }
        s16x8 af;
        af[0] = (short)f2bf(pa0.x); af[1] = (short)f2bf(pa0.y);
        af[2] = (short)f2bf(pa0.z); af[3] = (short)f2bf(pa0.w);
        af[4] = (short)f2bf(pa1.x); af[5] = (short)f2bf(pa1.y);
        af[6] = (short)f2bf(pa1.z); af[7] = (short)f2bf(pa1.w);
        int akoct = t * 4 + lk;
#pragma unroll
        for (int ni = 0; ni < 4; ++ni) {
            int bg = ni * 16 + lan;
            s16x8 bf = Tl[bg * 64 + (akoct ^ (bg & 7))];
            acc[ni] = __builtin_amdgcn_mfma_f32_16x16x32_bf16(af, bf, acc[ni], 0, 0, 0);
        }
        pa0 = pb0; pa1 = pb1; pb0 = pc0; pb1 = pc1;
    }

#pragma unroll
    for (int ni = 0; ni < 4; ++ni) {
        int bg = ni * 16 + lan;
        float4 o;
        o.x = acc[ni][0]; o.y = acc[ni][1]; o.z = acc[ni][2]; o.w = acc[ni][3];
        *(float4*)(out + (size_t)bg * 32000 + v0 + lk * 4) = o;
    }
}

// ---------------------------------------------------------------------------
extern "C" void kernel_launch(void* const* d_in, const int* in_sizes, int n_in,
                              void* d_out, int out_size, void* d_ws, size_t ws_size,
                              hipStream_t stream) {
    const int*      tok   = (const int*)d_in[0];
    const float*    h0    = (const float*)d_in[1];
    const float*    c0    = (const float*)d_in[2];
    const float*    enc   = (const float*)d_in[3];
    const unsigned* mask  = (const unsigned*)d_in[4];
    const float*    table = (const float*)d_in[5];
    const float*    We    = (const float*)d_in[6];
    const float*    Wd    = (const float*)d_in[7];
    const float*    va    = (const float*)d_in[8];
    const float*    Wih   = (const float*)d_in[9];
    const float*    Whh   = (const float*)d_in[10];
    const float*    bih   = (const float*)d_in[11];
    const float*    bhh   = (const float*)d_in[12];
    const float*    Wo    = (const float*)d_in[13];
    const float*    bo    = (const float*)d_in[14];

    float* out    = (float*)d_out;
    float* logits = out;                      // 64*32000 = 2048000
    float* out_h  = out + 2048000;            // 65536
    float* out_c  = out + 2048000 + 65536;    // 65536
    float* out_w  = out + 2048000 + 131072;   // 32768

    float* ws     = (float*)d_ws;
    float* emb    = ws;             // 32768
    float* dp     = ws + 32768;     // 16384
    float* scores = ws + 49152;     // 32768
    float* ctx    = ws + 81920;     // 65536
    float* big    = ws + 147456;    // 524288 floats (gates p7 / readout Tp)
    float* T      = ws + 671744;    // 32768
    ushort* Wbf   = (ushort*)(ws + 704512);   // 262144 bf16 (131072 float-slots)
    float* stats  = ws + 835584;    // 2048

    float* ctxp     = logits;       // 64*16*1024 = 1M floats, consumed by k_ctx_fin
    float* gates_p0 = logits;       // kc 0..6 partials (after ctxp consumed)
    float* gates_p7 = big;          // kc 7 partial
    float* Tp       = big;          // readout partials (after k_lstm consumed gates)

    k_prep        <<<384, 256, 0, stream>>>(tok, table, We, h0, Wd, emb, Wbf, dp);
    k_scores_ctx  <<<1024, 256, 0, stream>>>(enc, Wbf, dp, va, mask, scores, stats, ctxp);
    k_ctx_fin     <<<64, 256, 0, stream>>>(stats, scores, ctxp, out_w, ctx);
    k_gates_mfma  <<<dim3(64, 8), 256, 0, stream>>>(emb, ctx, h0, Wih, Whh, gates_p0, gates_p7);
    k_lstm        <<<256, 256, 0, stream>>>(gates_p0, gates_p7, bih, bhh, c0, out_h, out_c);
    k_readout_mfma<<<dim3(8, 16), 256, 0, stream>>>(out_h, ctx, emb, Wo, Tp);
    k_readout_fin <<<128, 256, 0, stream>>>(Tp, bo, T);
    k_logits      <<<500, 256, 0, stream>>>(T, table, logits);
}